// Round 7
// baseline (129.764 us; speedup 1.0000x reference)
//
#include <hip/hip_runtime.h>
#include <hip/hip_bf16.h>

// x[16,32,32,32,32] f32, w[32,64,3,3,3] f32, b[64] f32
// ConvTranspose3d(s=2,p=1,k=3) -> (+bias)*0.5 -> maxpool2 -> mean -> clamp[0,1] -> out[16,64]
//
// Window algebra (validated R0/R1): window w covers conv outputs {2w,2w+1}/dim,
// inputs {w,w+1}/dim; per-dim (delta,k,parity): (0,1,0) (0,2,1) (1,0,1). No bounds checks.
// MFMA 16x16x32 bf16: M=16 ww-windows, N=16 co, K=32=Cin (layouts verified R1).
//
// R7: latency restructure at fixed 2 waves/SIMD:
//  - block = (b, wd, whg of 16 wh): TWO sub-tiles of 8 wh, LDS double-buffer 2x36KB;
//    stage(buf1) issued BEFORE compute(buf0) -> barrier before compute(buf1) is cheap.
//  - rolling F prefetch (rows win..win+2, slot=row%3): next-row ds_reads issue before
//    current window's MFMAs; A-reads 8 -> 4.5 per window.
//  - strictly sequential parity classes, same-C back-to-back chains (full rate per m119);
//    C live = 4 + mx 4.
//
// ws: [0,4096)B accS[16][64] f32; [4096,...) wB bf16 [cotile4][T27][lane64][j8],
// T in class-sequential consumption order.

typedef __bf16 bf16x8 __attribute__((ext_vector_type(8)));
typedef float  f32x4  __attribute__((ext_vector_type(4)));
typedef unsigned short ushort_t;
typedef ushort_t ushort8 __attribute__((ext_vector_type(8)));

#define NWIN 29791  // 31^3

__device__ inline ushort_t f2bf(float f) {
    unsigned u = __builtin_bit_cast(unsigned, f);
    u += 0x7FFFu + ((u >> 16) & 1u);   // RNE
    return (ushort_t)(u >> 16);
}

// Class-sequential tap order (kd,kh,kw), classes: (111)x8,(011)x4,(101)x4,(110)x4,
// (001)x2,(010)x2,(100)x2,(000)x1
__device__ __constant__ const unsigned char TKD[27] =
    {0,2,0,2,0,2,0,2, 1,1,1,1, 0,2,0,2, 0,2,0,2, 1,1, 1,1, 0,2, 1};
__device__ __constant__ const unsigned char TKH[27] =
    {0,0,2,2,0,0,2,2, 0,2,0,2, 1,1,1,1, 0,0,2,2, 1,1, 0,2, 1,1, 1};
__device__ __constant__ const unsigned char TKW[27] =
    {0,0,0,0,2,2,2,2, 0,0,2,2, 0,0,2,2, 1,1,1,1, 0,2, 1,1, 1,1, 1};

__global__ __launch_bounds__(256) void prep_kernel(const float* __restrict__ w,
                                                   float* __restrict__ ws) {
    int idx = blockIdx.x * 256 + threadIdx.x;
    if (idx < 1024) ws[idx] = 0.f;
    if (idx < 55296) {
        ushort_t* wB = (ushort_t*)((char*)ws + 4096);
        int j = idx & 7;
        int l = (idx >> 3) & 63;
        int q = idx >> 9;           // [0,108) = c*27+T
        int T = q % 27;
        int c = q / 27;
        int ci = ((l >> 4) << 3) + j;
        int co = (c << 4) + (l & 15);
        int k3 = TKD[T] * 9 + TKH[T] * 3 + TKW[T];
        wB[idx] = f2bf(w[(ci * 64 + co) * 27 + k3]);
    }
}

// grid = 16 b * 31 wd * 2 whg, 256 threads
__global__ __launch_bounds__(256, 2) void main_kernel(const float* __restrict__ x,
                                                      const float* __restrict__ ws_ro,
                                                      float* __restrict__ accS) {
    __shared__ ushort_t xT[2][18432];  // [dd2][hh9][w32][ci32] bf16, s = kq ^ ((w>>1)&3)

    int bid = blockIdx.x;
    int b   = bid / 62;             // 31*2
    int r   = bid - b * 62;
    int wd  = r >> 1;               // [0,31)
    int whg = r & 1;                // wh group of 16 (2 sub-tiles of 8)
    int tid = threadIdx.x;
    int lane = tid & 63;
    int wave = tid >> 6;
    int uw   = __builtin_amdgcn_readfirstlane(wave);

    // ---- this wave's 27 weight B-frags (consumption order) -> acc regs
    const bf16x8* wBv = (const bf16x8*)((const char*)ws_ro + 4096);
    bf16x8 Bf[27];
#pragma unroll
    for (int t = 0; t < 27; ++t) Bf[t] = wBv[(uw * 27 + t) * 64 + lane];

    // ---- staging helper: wave uw stages ci planes [8uw,8uw+8), 9 h-rows from h=hb
    int sdd = lane >> 5;
    int swl = lane & 31;
    const float* xb = x + ((size_t)(b * 32 + uw * 8)) * 32768u + ((size_t)(wd + 1) << 10);
    int voff = (sdd - 1) * 1024 + swl;
    int ss   = uw ^ ((swl >> 1) & 3);
    int doff = ((sdd * 9) << 10) + (swl << 5) + (ss << 3);

    auto stage = [&](ushort_t* buf, int hb) {
        int ro8 = (hb == 24) ? 7 * 32 : 8 * 32;   // clamp h=32 -> 31 (feeds masked wh=31 only)
        const float* src = xb + ((size_t)hb << 5) + voff;
        ushort_t* dst = buf + doff;
#pragma unroll
        for (int rr = 0; rr < 9; ++rr) {
            int ro = (rr < 8) ? rr * 32 : ro8;
            float v[8];
#pragma unroll
            for (int i = 0; i < 8; ++i) v[i] = src[(size_t)i * 32768u + ro];
            ushort8 pk;
#pragma unroll
            for (int i = 0; i < 4; ++i) {
                __hip_bfloat162 p2 = __float22bfloat162_rn(float2{v[2 * i], v[2 * i + 1]});
                pk[2 * i]     = __builtin_bit_cast(ushort_t, p2.x);
                pk[2 * i + 1] = __builtin_bit_cast(ushort_t, p2.y);
            }
            *(ushort8*)&dst[rr << 10] = pk;
        }
    };

    int m  = lane & 15;
    int kq = lane >> 4;
    float runsum = 0.f;
    const f32x4 Z = (f32x4){0.f, 0.f, 0.f, 0.f};

    // per-tap frag index (dd, dh-slot-sel, dw) and class boundaries
    static constexpr int FDD[27] = {1,0,1,0,1,0,1,0, 0,0,0,0, 1,0,1,0, 1,0,1,0, 0,0, 0,0, 1,0, 0};
    static constexpr int FDH[27] = {1,1,0,0,1,1,0,0, 1,0,1,0, 0,0,0,0, 1,1,0,0, 0,0, 1,0, 0,0, 0};
    static constexpr int FDW[27] = {1,1,1,1,0,0,0,0, 1,1,0,0, 1,1,0,0, 0,0,0,0, 1,0, 0,0, 0,0, 0};
    static constexpr int CSTART[9] = {0, 8, 12, 16, 20, 22, 24, 26, 27};

    auto compute = [&](const ushort_t* base, int whb) {
#pragma unroll 1
        for (int half = 0; half < 2; ++half) {
            int wbase = half << 4;
            int w0 = wbase + m;                    // <= 31
            int w1 = w0 + 1; if (w1 > 31) w1 = 31; // garbage -> window 31, masked
            int col0 = (w0 << 5) + ((kq ^ ((w0 >> 1) & 3)) << 3);
            int col1 = (w1 << 5) + ((kq ^ ((w1 >> 1) & 3)) << 3);

            bf16x8 Fr[2][3][2];   // [dd][row%3][dw]
#pragma unroll
            for (int rr = 0; rr < 2; ++rr)
#pragma unroll
                for (int dd = 0; dd < 2; ++dd) {
                    int row = (dd * 9 + rr) << 10;
                    Fr[dd][rr][0] = *(const bf16x8*)&base[row + col0];
                    Fr[dd][rr][1] = *(const bf16x8*)&base[row + col1];
                }

#pragma unroll
            for (int win = 0; win < 8; ++win) {
                const int s0 = win % 3, s1 = (win + 1) % 3;
                // prefetch next row's 4 frags before this window's MFMAs
                if (win < 7) {
                    const int rn = win + 2, sl = (win + 2) % 3;
#pragma unroll
                    for (int dd = 0; dd < 2; ++dd) {
                        int row = (dd * 9 + rn) << 10;
                        Fr[dd][sl][0] = *(const bf16x8*)&base[row + col0];
                        Fr[dd][sl][1] = *(const bf16x8*)&base[row + col1];
                    }
                }

                f32x4 mx;
#pragma unroll
                for (int c = 0; c < 8; ++c) {
                    f32x4 C;
#pragma unroll
                    for (int i = CSTART[c]; i < CSTART[c + 1]; ++i) {
                        C = __builtin_amdgcn_mfma_f32_16x16x32_bf16(
                            Fr[FDD[i]][FDH[i] ? s1 : s0][FDW[i]], Bf[i],
                            (i == CSTART[c]) ? Z : C, 0, 0, 0);
                    }
#pragma unroll
                    for (int q = 0; q < 4; ++q)
                        mx[q] = (c == 0) ? C[q] : fmaxf(mx[q], C[q]);
                }

                int wh = whb + win;
                if (wh < 31) {
#pragma unroll
                    for (int rr = 0; rr < 4; ++rr) {
                        int ww = wbase + (kq << 2) + rr;
                        if (ww < 31) runsum += mx[rr];
                    }
                }
            }
        }
    };

    int hb0 = whg << 4;
    stage(xT[0], hb0);
    __syncthreads();
    stage(xT[1], hb0 + 8);      // buf1 staged before compute0 -> latency hidden
    compute(xT[0], hb0);
    __syncthreads();            // buf1 writes long since complete
    compute(xT[1], hb0 + 8);

    // lanes with same n=(lane&15) hold partials for the same co
    runsum += __shfl_xor(runsum, 16, 64);
    runsum += __shfl_xor(runsum, 32, 64);
    if (lane < 16) atomicAdd(&accS[(b << 6) + (wave << 4) + lane], runsum);
}

__global__ __launch_bounds__(256) void finalize_kernel(const float* __restrict__ accS,
                                                       const float* __restrict__ bias,
                                                       float* __restrict__ out) {
    int i = blockIdx.x * 256 + threadIdx.x;
    if (i < 1024) {
        int co = i & 63;
        float v = (accS[i] * (1.f / (float)NWIN) + bias[co]) * 0.5f;
        v = fminf(fmaxf(v, 0.f), 1.f);
        out[i] = v;
    }
}

extern "C" void kernel_launch(void* const* d_in, const int* in_sizes, int n_in,
                              void* d_out, int out_size, void* d_ws, size_t ws_size,
                              hipStream_t stream) {
    const float* x    = (const float*)d_in[0];
    const float* w    = (const float*)d_in[1];
    const float* bias = (const float*)d_in[2];
    float* out = (float*)d_out;
    float* ws  = (float*)d_ws;

    prep_kernel<<<216, 256, 0, stream>>>(w, ws);
    main_kernel<<<16 * 31 * 2, 256, 0, stream>>>(x, ws, ws);
    finalize_kernel<<<4, 256, 0, stream>>>(ws, bias, out);
}